// Round 1
// baseline (185.045 us; speedup 1.0000x reference)
//
#include <hip/hip_runtime.h>
#include <hip/hip_bf16.h>
#include <math.h>

typedef float f32x4 __attribute__((ext_vector_type(4)));
typedef __bf16 bf16_t;
typedef bf16_t bf16x8 __attribute__((ext_vector_type(8)));
typedef bf16_t bf16x4 __attribute__((ext_vector_type(4)));

// ---------------- fp32 -> bf16 conversion (vectorized) ----------------
__global__ __launch_bounds__(256) void cvt_f32_bf16(const float* __restrict__ in,
                                                    bf16_t* __restrict__ out, int n) {
    int i = (blockIdx.x * 256 + threadIdx.x) * 4;
    if (i >= n) return;
    float4 v = *reinterpret_cast<const float4*>(in + i);
    bf16x4 o;
    o[0] = (bf16_t)v.x; o[1] = (bf16_t)v.y; o[2] = (bf16_t)v.z; o[3] = (bf16_t)v.w;
    *reinterpret_cast<bf16x4*>(out + i) = o;
}

// ---------------- bf16 GEMM: C = A @ B^T (+bias, epilogue) ----------------
// A: M x K row-major bf16, B: N x K row-major bf16.
// EPI 0: qkvg epilogue (softplus/softplus/gelu/gelu by col>>10), store bf16.
// EPI 1: proj epilogue (+bias), store fp32.
template<int EPI>
__global__ __launch_bounds__(256) void gemm_bt(const bf16_t* __restrict__ A,
                                               const bf16_t* __restrict__ B,
                                               const float* __restrict__ bias,
                                               void* __restrict__ Cout,
                                               int M, int N, int K) {
    __shared__ bf16_t As[128 * 32];
    __shared__ bf16_t Bs[128 * 32];
    const int tid = threadIdx.x;
    const int lane = tid & 63;
    const int w = tid >> 6;
    const int wr = w >> 1, wc = w & 1;
    const int m0 = blockIdx.y * 128, n0 = blockIdx.x * 128;
    const int l15 = lane & 15, lg = lane >> 4;

    f32x4 acc[4][4] = {};

    for (int k0 = 0; k0 < K; k0 += 32) {
        __syncthreads();
        // stage A-tile (128x32) and B-tile (128x32), 8 bf16 per load,
        // 16B-chunk index XOR-swizzled by row to break bank conflicts.
#pragma unroll
        for (int it = 0; it < 2; ++it) {
            int idx = tid + it * 256;        // 0..511
            int row = idx >> 2, ch = idx & 3;
            int chs = ch ^ (row & 3);
            *(bf16x8*)(&As[row * 32 + chs * 8]) =
                *(const bf16x8*)(&A[(size_t)(m0 + row) * K + k0 + ch * 8]);
            *(bf16x8*)(&Bs[row * 32 + chs * 8]) =
                *(const bf16x8*)(&B[(size_t)(n0 + row) * K + k0 + ch * 8]);
        }
        __syncthreads();

        bf16x8 af[4], bfr[4];
#pragma unroll
        for (int i = 0; i < 4; ++i) {
            int ar = wr * 64 + i * 16 + l15;
            af[i] = *(const bf16x8*)(&As[ar * 32 + (lg ^ (ar & 3)) * 8]);
            int br = wc * 64 + i * 16 + l15;
            bfr[i] = *(const bf16x8*)(&Bs[br * 32 + (lg ^ (br & 3)) * 8]);
        }
#pragma unroll
        for (int i = 0; i < 4; ++i)
#pragma unroll
            for (int j = 0; j < 4; ++j)
                acc[i][j] = __builtin_amdgcn_mfma_f32_16x16x32_bf16(af[i], bfr[j], acc[i][j], 0, 0, 0);
    }

    // epilogue: C/D layout col = lane&15, row = (lane>>4)*4 + reg  [verified]
#pragma unroll
    for (int i = 0; i < 4; ++i) {
        int gm_base = m0 + wr * 64 + i * 16 + lg * 4;
#pragma unroll
        for (int j = 0; j < 4; ++j) {
            int gn = n0 + wc * 64 + j * 16 + l15;
            float bv = bias[gn];
#pragma unroll
            for (int r = 0; r < 4; ++r) {
                int gm = gm_base + r;
                float v = acc[i][j][r] + bv;
                if (EPI == 0) {
                    float a;
                    if ((gn >> 10) < 2) {
                        // stable softplus: max(x,0) + log1p(exp(-|x|))
                        a = fmaxf(v, 0.f) + log1pf(expf(-fabsf(v)));
                    } else {
                        // exact gelu: x * 0.5 * (1 + erf(x/sqrt(2)))
                        a = 0.5f * v * (1.f + erff(v * 0.70710678118654752f));
                    }
                    ((bf16_t*)Cout)[(size_t)gm * N + gn] = (bf16_t)a;
                } else {
                    ((float*)Cout)[(size_t)gm * N + gn] = v;
                }
            }
        }
    }
}

// ---------------- A = K^T Q partials per (b,h), 4 token chunks ----------------
// qkvg layout: [(b*1024+n)*4096 + s*1024 + h*64 + e], s in {q,k,v,g}
__global__ __launch_bounds__(256) void attn_A(const bf16_t* __restrict__ qkvg,
                                              float* __restrict__ Apart) {
    const int bh = blockIdx.x;           // 0..31
    const int p = blockIdx.y;            // 0..3
    const int b = bh >> 4, h = bh & 15;
    const int tid = threadIdx.x;
    __shared__ float ks[32][64];
    __shared__ float qs[32][64];
    float acc[4][4] = {};
    const int dg = tid >> 4, eg = tid & 15;
    const size_t base = ((size_t)b * 1024) * 4096 + (size_t)h * 64;

    for (int t0 = p * 256; t0 < p * 256 + 256; t0 += 32) {
        __syncthreads();
#pragma unroll
        for (int i = 0; i < 8; ++i) {
            int lin = tid + i * 256;
            int tok = lin >> 6, e = lin & 63;
            size_t rowb = base + (size_t)(t0 + tok) * 4096;
            qs[tok][e] = (float)qkvg[rowb + e];          // q
            ks[tok][e] = (float)qkvg[rowb + 1024 + e];   // k
        }
        __syncthreads();
#pragma unroll 8
        for (int tt = 0; tt < 32; ++tt) {
            f32x4 kv = *(const f32x4*)(&ks[tt][dg * 4]);
            f32x4 qv = *(const f32x4*)(&qs[tt][eg * 4]);
#pragma unroll
            for (int i = 0; i < 4; ++i)
#pragma unroll
                for (int j = 0; j < 4; ++j) acc[i][j] += kv[i] * qv[j];
        }
    }
    float* dst = Apart + ((size_t)p * 32 + bh) * 4096;
#pragma unroll
    for (int i = 0; i < 4; ++i)
#pragma unroll
        for (int j = 0; j < 4; ++j)
            dst[(dg * 4 + i) * 64 + eg * 4 + j] = acc[i][j];
}

// ---------------- reduce partials -> A, compute z ----------------
__global__ __launch_bounds__(256) void reduce_A_z(const float* __restrict__ Apart,
                                                  float* __restrict__ A,
                                                  float* __restrict__ z) {
    const int bh = blockIdx.x;
    const int tid = threadIdx.x;
    __shared__ float As[4096];
    for (int i = tid; i < 4096; i += 256) {
        float s = 0.f;
#pragma unroll
        for (int p = 0; p < 4; ++p) s += Apart[((size_t)p * 32 + bh) * 4096 + i];
        As[i] = s;
        A[(size_t)bh * 4096 + i] = s;
    }
    __syncthreads();
    if (tid < 64) {
        float s = 0.f;
#pragma unroll 8
        for (int d = 0; d < 64; ++d) s += As[d * 64 + tid];
        z[bh * 64 + tid] = 1.0f / (s * 0.125f + 1024.0f);
    }
}

// ---------------- Y = ((SCALE*V@A + V) * z * g), scrambled-reshaped, bf16 ----------------
__global__ __launch_bounds__(256) void out_Y(const bf16_t* __restrict__ qkvg,
                                             const float* __restrict__ A,
                                             const float* __restrict__ z,
                                             bf16_t* __restrict__ Y) {
    const int bh = blockIdx.x;
    const int b = bh >> 4, h = bh & 15;
    const int chunk = blockIdx.y;        // 0..7 -> 128 tokens
    const int tid = threadIdx.x;
    __shared__ float As[64][64];         // A[d][e]
    __shared__ float vs[32][64];
    __shared__ float zs[64];
    for (int i = tid; i < 4096; i += 256) As[i >> 6][i & 63] = A[(size_t)bh * 4096 + i];
    if (tid < 64) zs[tid] = z[bh * 64 + tid];
    const size_t base = ((size_t)b * 1024) * 4096 + (size_t)h * 64;
    const int e = tid & 63, trow = tid >> 6;

    for (int t0 = chunk * 128; t0 < chunk * 128 + 128; t0 += 32) {
        __syncthreads();
#pragma unroll
        for (int i = 0; i < 8; ++i) {
            int lin = tid + i * 256;
            int tok = lin >> 6, ee = lin & 63;
            vs[tok][ee] = (float)qkvg[base + (size_t)(t0 + tok) * 4096 + 2048 + ee];
        }
        __syncthreads();
#pragma unroll
        for (int kk = 0; kk < 8; ++kk) {
            int ml = trow * 8 + kk;
            int m = t0 + ml;
            float s = 0.f;
#pragma unroll 8
            for (int d = 0; d < 64; ++d) s += vs[ml][d] * As[d][e];
            float g = (float)qkvg[base + (size_t)m * 4096 + 3072 + e];
            float o = (s * 0.125f + vs[ml][e]) * zs[e] * g;
            Y[((size_t)b * 1024 + h * 64 + (m >> 4)) * 1024 + ((m & 15) << 6) + e] = (bf16_t)o;
        }
    }
}

extern "C" void kernel_launch(void* const* d_in, const int* in_sizes, int n_in,
                              void* d_out, int out_size, void* d_ws, size_t ws_size,
                              hipStream_t stream) {
    const float* x      = (const float*)d_in[0];
    const float* w_qkvg = (const float*)d_in[1];
    const float* b_qkvg = (const float*)d_in[2];
    const float* w_proj = (const float*)d_in[3];
    const float* b_proj = (const float*)d_in[4];

    char* p = (char*)d_ws;
    bf16_t* xb    = (bf16_t*)p; p += (size_t)2048 * 1024 * 2;
    bf16_t* w1b   = (bf16_t*)p; p += (size_t)4096 * 1024 * 2;
    bf16_t* w2b   = (bf16_t*)p; p += (size_t)1024 * 1024 * 2;
    bf16_t* qkvg  = (bf16_t*)p; p += (size_t)2048 * 4096 * 2;
    float*  Apart = (float*)p;  p += (size_t)4 * 32 * 4096 * 4;
    float*  Afull = (float*)p;  p += (size_t)32 * 4096 * 4;
    float*  zbuf  = (float*)p;  p += (size_t)32 * 64 * 4;
    bf16_t* Ybuf  = (bf16_t*)p; p += (size_t)2048 * 1024 * 2;

    cvt_f32_bf16<<<2048, 256, 0, stream>>>(x, xb, 2048 * 1024);
    cvt_f32_bf16<<<4096, 256, 0, stream>>>(w_qkvg, w1b, 4096 * 1024);
    cvt_f32_bf16<<<1024, 256, 0, stream>>>(w_proj, w2b, 1024 * 1024);

    gemm_bt<0><<<dim3(32, 16), 256, 0, stream>>>(xb, w1b, b_qkvg, (void*)qkvg, 2048, 4096, 1024);
    attn_A<<<dim3(32, 4), 256, 0, stream>>>(qkvg, Apart);
    reduce_A_z<<<32, 256, 0, stream>>>(Apart, Afull, zbuf);
    out_Y<<<dim3(32, 8), 256, 0, stream>>>(qkvg, Afull, zbuf, Ybuf);
    gemm_bt<1><<<dim3(8, 16), 256, 0, stream>>>(Ybuf, w2b, b_proj, d_out, 2048, 1024, 1024);
}

// Round 2
// 178.079 us; speedup vs baseline: 1.0391x; 1.0391x over previous
//
#include <hip/hip_runtime.h>
#include <hip/hip_bf16.h>
#include <math.h>

typedef float f32x4 __attribute__((ext_vector_type(4)));
typedef __bf16 bf16_t;
typedef bf16_t bf16x8 __attribute__((ext_vector_type(8)));
typedef bf16_t bf16x4 __attribute__((ext_vector_type(4)));

// async global->LDS, 16B per lane; LDS dest = wave-uniform base + lane*16
__device__ __forceinline__ void gload_lds16(const bf16_t* g, bf16_t* l) {
    __builtin_amdgcn_global_load_lds(
        (const __attribute__((address_space(1))) unsigned int*)g,
        (__attribute__((address_space(3))) unsigned int*)l, 16, 0, 0);
}

// ---------------- fused fp32 -> bf16 conversion for 3 arrays ----------------
__global__ __launch_bounds__(256) void cvt3(const float* __restrict__ a, bf16_t* __restrict__ ao, int na4,
                                            const float* __restrict__ b, bf16_t* __restrict__ bo, int nb4,
                                            const float* __restrict__ c, bf16_t* __restrict__ co, int nc4) {
    int q = blockIdx.x * 256 + threadIdx.x;   // quad index
    const float* src; bf16_t* dst;
    if (q < na4)            { src = a + (size_t)q * 4;              dst = ao + (size_t)q * 4; }
    else if (q < na4 + nb4) { int r = q - na4; src = b + (size_t)r * 4; dst = bo + (size_t)r * 4; }
    else if (q < na4 + nb4 + nc4) { int r = q - na4 - nb4; src = c + (size_t)r * 4; dst = co + (size_t)r * 4; }
    else return;
    float4 v = *reinterpret_cast<const float4*>(src);
    bf16x4 o;
    o[0] = (bf16_t)v.x; o[1] = (bf16_t)v.y; o[2] = (bf16_t)v.z; o[3] = (bf16_t)v.w;
    *reinterpret_cast<bf16x4*>(dst) = o;
}

// ---------------- bf16 GEMM: C = A @ B^T (+bias, epilogue) ----------------
// m97 structure: global_load_lds width-16 staging into linear LDS,
// source-preswizzled (ch = pos ^ ((row>>1)&3)) so swizzled ds_read_b128 is 2-way max.
// EPI 0: qkvg epilogue (softplus x2 / gelu x2 by col>>10), store bf16.
// EPI 1: proj epilogue (+bias), store fp32.
template<int BM, int BN, int MR, int NR, int EPI>
__global__ __launch_bounds__(256) void gemm_bt(const bf16_t* __restrict__ A,
                                               const bf16_t* __restrict__ B,
                                               const float* __restrict__ bias,
                                               void* __restrict__ Cout,
                                               int M, int N, int K) {
    constexpr int WCOLS = BN / (NR * 16);
    constexpr int WROWS = BM / (MR * 16);
    static_assert(WROWS * WCOLS == 4, "4 waves");
    __shared__ bf16_t As[BM * 32];
    __shared__ bf16_t Bs[BN * 32];
    const int tid = threadIdx.x;
    const int lane = tid & 63;
    const int w = tid >> 6;
    const int wr = w / WCOLS, wc = w % WCOLS;
    const int m0 = blockIdx.y * BM, n0 = blockIdx.x * BN;
    const int l15 = lane & 15, lg = lane >> 4;
    const int srow_off = lane >> 2, pos = lane & 3;

    f32x4 acc[MR][NR] = {};

    for (int k0 = 0; k0 < K; k0 += 32) {
        // stage: each wave writes contiguous 1KB segments (16 rows x 64B), linear LDS;
        // global chunk pre-swizzled so LDS slot (row,pos) holds chunk pos^((row>>1)&3)
#pragma unroll
        for (int t = 0; t < BM / 64; ++t) {
            int s = w + t * 4;
            int row = s * 16 + srow_off;
            int ch = pos ^ ((row >> 1) & 3);
            gload_lds16(&A[(size_t)(m0 + row) * K + k0 + ch * 8], &As[s * 512]);
        }
#pragma unroll
        for (int t = 0; t < BN / 64; ++t) {
            int s = w + t * 4;
            int row = s * 16 + srow_off;
            int ch = pos ^ ((row >> 1) & 3);
            gload_lds16(&B[(size_t)(n0 + row) * K + k0 + ch * 8], &Bs[s * 512]);
        }
        __syncthreads();

        bf16x8 af[MR], bfr[NR];
#pragma unroll
        for (int i = 0; i < MR; ++i) {
            int ar = wr * MR * 16 + i * 16 + l15;
            af[i] = *(const bf16x8*)(&As[ar * 32 + (lg ^ ((ar >> 1) & 3)) * 8]);
        }
#pragma unroll
        for (int j = 0; j < NR; ++j) {
            int br = wc * NR * 16 + j * 16 + l15;
            bfr[j] = *(const bf16x8*)(&Bs[br * 32 + (lg ^ ((br >> 1) & 3)) * 8]);
        }
#pragma unroll
        for (int i = 0; i < MR; ++i)
#pragma unroll
            for (int j = 0; j < NR; ++j)
                acc[i][j] = __builtin_amdgcn_mfma_f32_16x16x32_bf16(af[i], bfr[j], acc[i][j], 0, 0, 0);
        __syncthreads();
    }

    // epilogue: C/D layout col = lane&15, row = (lane>>4)*4 + reg
#pragma unroll
    for (int i = 0; i < MR; ++i) {
        int gm_base = m0 + wr * MR * 16 + i * 16 + lg * 4;
#pragma unroll
        for (int j = 0; j < NR; ++j) {
            int gn = n0 + wc * NR * 16 + j * 16 + l15;
            float bv = bias[gn];
#pragma unroll
            for (int r = 0; r < 4; ++r) {
                int gm = gm_base + r;
                float v = acc[i][j][r] + bv;
                if (EPI == 0) {
                    float a;
                    if ((gn >> 10) < 2) {
                        a = fmaxf(v, 0.f) + log1pf(expf(-fabsf(v)));          // softplus
                    } else {
                        a = 0.5f * v * (1.f + erff(v * 0.70710678118654752f)); // exact gelu
                    }
                    ((bf16_t*)Cout)[(size_t)gm * N + gn] = (bf16_t)a;
                } else {
                    ((float*)Cout)[(size_t)gm * N + gn] = v;
                }
            }
        }
    }
}

// ---------------- A = K^T Q partials per (b,h), 4 token chunks ----------------
// qkvg layout: [(b*1024+n)*4096 + s*1024 + h*64 + e], s in {q,k,v,g}
__global__ __launch_bounds__(256) void attn_A(const bf16_t* __restrict__ qkvg,
                                              float* __restrict__ Apart) {
    const int bh = blockIdx.x;           // 0..31
    const int p = blockIdx.y;            // 0..3
    const int b = bh >> 4, h = bh & 15;
    const int tid = threadIdx.x;
    __shared__ float ks[32][64];
    __shared__ float qs[32][64];
    float acc[4][4] = {};
    const int dg = tid >> 4, eg = tid & 15;
    const int stok = tid >> 3, se0 = (tid & 7) * 8;
    const size_t base = ((size_t)b * 1024) * 4096 + (size_t)h * 64;

    for (int t0 = p * 256; t0 < p * 256 + 256; t0 += 32) {
        __syncthreads();
        size_t rowb = base + (size_t)(t0 + stok) * 4096;
        bf16x8 qv8 = *(const bf16x8*)(&qkvg[rowb + se0]);
        bf16x8 kv8 = *(const bf16x8*)(&qkvg[rowb + 1024 + se0]);
#pragma unroll
        for (int jj = 0; jj < 8; ++jj) {
            qs[stok][se0 + jj] = (float)qv8[jj];
            ks[stok][se0 + jj] = (float)kv8[jj];
        }
        __syncthreads();
#pragma unroll 8
        for (int tt = 0; tt < 32; ++tt) {
            f32x4 kv = *(const f32x4*)(&ks[tt][dg * 4]);
            f32x4 qv = *(const f32x4*)(&qs[tt][eg * 4]);
#pragma unroll
            for (int i = 0; i < 4; ++i)
#pragma unroll
                for (int j = 0; j < 4; ++j) acc[i][j] += kv[i] * qv[j];
        }
    }
    float* dst = Apart + ((size_t)p * 32 + bh) * 4096;
#pragma unroll
    for (int i = 0; i < 4; ++i)
#pragma unroll
        for (int j = 0; j < 4; ++j)
            dst[(dg * 4 + i) * 64 + eg * 4 + j] = acc[i][j];
}

// ---------------- reduce partials -> A, compute z ----------------
__global__ __launch_bounds__(256) void reduce_A_z(const float* __restrict__ Apart,
                                                  float* __restrict__ A,
                                                  float* __restrict__ z) {
    const int bh = blockIdx.x;
    const int tid = threadIdx.x;
    __shared__ float As[4096];
    for (int i0 = tid * 4; i0 < 4096; i0 += 1024) {
        f32x4 s = {};
#pragma unroll
        for (int p = 0; p < 4; ++p) {
            f32x4 v = *(const f32x4*)(&Apart[((size_t)p * 32 + bh) * 4096 + i0]);
            s += v;
        }
        *(f32x4*)(&As[i0]) = s;
        *(f32x4*)(&A[(size_t)bh * 4096 + i0]) = s;
    }
    __syncthreads();
    if (tid < 64) {
        float s = 0.f;
#pragma unroll 8
        for (int d = 0; d < 64; ++d) s += As[d * 64 + tid];
        z[bh * 64 + tid] = 1.0f / (s * 0.125f + 1024.0f);
    }
}

// ---------------- Y = ((SCALE*V@A + V) * z * g), scrambled-reshaped, bf16 ----------------
__global__ __launch_bounds__(256) void out_Y(const bf16_t* __restrict__ qkvg,
                                             const float* __restrict__ A,
                                             const float* __restrict__ z,
                                             bf16_t* __restrict__ Y) {
    const int bh = blockIdx.x;
    const int b = bh >> 4, h = bh & 15;
    const int chunk = blockIdx.y;        // 0..7 -> 128 tokens
    const int tid = threadIdx.x;
    __shared__ float As[64][64];         // A[d][e]
    __shared__ float vs[32][64];
    __shared__ float zs[64];
    for (int i = tid; i < 4096; i += 256) As[i >> 6][i & 63] = A[(size_t)bh * 4096 + i];
    if (tid < 64) zs[tid] = z[bh * 64 + tid];
    const size_t base = ((size_t)b * 1024) * 4096 + (size_t)h * 64;
    const int e = tid & 63, trow = tid >> 6;
    const int stok = tid >> 3, se0 = (tid & 7) * 8;

    for (int t0 = chunk * 128; t0 < chunk * 128 + 128; t0 += 32) {
        __syncthreads();
        bf16x8 vv8 = *(const bf16x8*)(&qkvg[base + (size_t)(t0 + stok) * 4096 + 2048 + se0]);
#pragma unroll
        for (int jj = 0; jj < 8; ++jj) vs[stok][se0 + jj] = (float)vv8[jj];
        __syncthreads();
#pragma unroll
        for (int kk = 0; kk < 8; ++kk) {
            int ml = trow * 8 + kk;
            int m = t0 + ml;
            float s = 0.f;
#pragma unroll 8
            for (int d = 0; d < 64; ++d) s += vs[ml][d] * As[d][e];
            float g = (float)qkvg[base + (size_t)m * 4096 + 3072 + e];
            float o = (s * 0.125f + vs[ml][e]) * zs[e] * g;
            Y[((size_t)b * 1024 + h * 64 + (m >> 4)) * 1024 + ((m & 15) << 6) + e] = (bf16_t)o;
        }
    }
}

extern "C" void kernel_launch(void* const* d_in, const int* in_sizes, int n_in,
                              void* d_out, int out_size, void* d_ws, size_t ws_size,
                              hipStream_t stream) {
    const float* x      = (const float*)d_in[0];
    const float* w_qkvg = (const float*)d_in[1];
    const float* b_qkvg = (const float*)d_in[2];
    const float* w_proj = (const float*)d_in[3];
    const float* b_proj = (const float*)d_in[4];

    char* p = (char*)d_ws;
    bf16_t* xb    = (bf16_t*)p; p += (size_t)2048 * 1024 * 2;
    bf16_t* w1b   = (bf16_t*)p; p += (size_t)4096 * 1024 * 2;
    bf16_t* w2b   = (bf16_t*)p; p += (size_t)1024 * 1024 * 2;
    bf16_t* qkvg  = (bf16_t*)p; p += (size_t)2048 * 4096 * 2;
    float*  Apart = (float*)p;  p += (size_t)4 * 32 * 4096 * 4;
    float*  Afull = (float*)p;  p += (size_t)32 * 4096 * 4;
    float*  zbuf  = (float*)p;  p += (size_t)32 * 64 * 4;
    bf16_t* Ybuf  = (bf16_t*)p; p += (size_t)2048 * 1024 * 2;

    // quad counts: x 524288, w_qkvg 1048576, w_proj 262144 -> 7168 blocks
    cvt3<<<7168, 256, 0, stream>>>(x, xb, 524288, w_qkvg, w1b, 1048576, w_proj, w2b, 262144);

    gemm_bt<128, 128, 4, 4, 0><<<dim3(32, 16), 256, 0, stream>>>(xb, w1b, b_qkvg, (void*)qkvg, 2048, 4096, 1024);
    attn_A<<<dim3(32, 4), 256, 0, stream>>>(qkvg, Apart);
    reduce_A_z<<<32, 256, 0, stream>>>(Apart, Afull, zbuf);
    out_Y<<<dim3(32, 8), 256, 0, stream>>>(qkvg, Afull, zbuf, Ybuf);
    gemm_bt<64, 128, 4, 2, 1><<<dim3(8, 32), 256, 0, stream>>>(Ybuf, w2b, b_proj, d_out, 2048, 1024, 1024);
}

// Round 3
// 101.836 us; speedup vs baseline: 1.8171x; 1.7487x over previous
//
#include <hip/hip_runtime.h>
#include <hip/hip_bf16.h>
#include <math.h>

typedef float f32x4 __attribute__((ext_vector_type(4)));
typedef __bf16 bf16_t;
typedef bf16_t bf16x8 __attribute__((ext_vector_type(8)));
typedef bf16_t bf16x4 __attribute__((ext_vector_type(4)));

// async global->LDS, 16B per lane; LDS dest = wave-uniform base + lane*16
__device__ __forceinline__ void gload_lds16(const bf16_t* g, bf16_t* l) {
    __builtin_amdgcn_global_load_lds(
        (const __attribute__((address_space(1))) unsigned int*)g,
        (__attribute__((address_space(3))) unsigned int*)l, 16, 0, 0);
}

template<int N_IMM>
__device__ __forceinline__ void wait_vmcnt() {
    if constexpr (N_IMM == 0) asm volatile("s_waitcnt vmcnt(0)" ::: "memory");
    else if constexpr (N_IMM == 1) asm volatile("s_waitcnt vmcnt(1)" ::: "memory");
    else if constexpr (N_IMM == 2) asm volatile("s_waitcnt vmcnt(2)" ::: "memory");
    else if constexpr (N_IMM == 3) asm volatile("s_waitcnt vmcnt(3)" ::: "memory");
    else if constexpr (N_IMM == 4) asm volatile("s_waitcnt vmcnt(4)" ::: "memory");
    else static_assert(N_IMM <= 4, "unsupported vmcnt");
}

// ---------------- fused fp32 -> bf16 conversion for 3 arrays ----------------
__global__ __launch_bounds__(256) void cvt3(const float* __restrict__ a, bf16_t* __restrict__ ao, int na4,
                                            const float* __restrict__ b, bf16_t* __restrict__ bo, int nb4,
                                            const float* __restrict__ c, bf16_t* __restrict__ co, int nc4) {
    int q = blockIdx.x * 256 + threadIdx.x;   // quad index
    const float* src; bf16_t* dst;
    if (q < na4)            { src = a + (size_t)q * 4;              dst = ao + (size_t)q * 4; }
    else if (q < na4 + nb4) { int r = q - na4; src = b + (size_t)r * 4; dst = bo + (size_t)r * 4; }
    else if (q < na4 + nb4 + nc4) { int r = q - na4 - nb4; src = c + (size_t)r * 4; dst = co + (size_t)r * 4; }
    else return;
    float4 v = *reinterpret_cast<const float4*>(src);
    bf16x4 o;
    o[0] = (bf16_t)v.x; o[1] = (bf16_t)v.y; o[2] = (bf16_t)v.z; o[3] = (bf16_t)v.w;
    *reinterpret_cast<bf16x4*>(dst) = o;
}

// ---------------- bf16 GEMM: C = A @ B^T (+bias, epilogue) ----------------
// 2-phase double-buffered pipeline (T3-min): raw s_barrier + counted vmcnt so
// next-tile global_load_lds stays in flight across the barrier.
// Staging into linear LDS, source-preswizzled (ch = pos ^ ((row>>1)&3));
// swizzled ds_read_b128 -> 0 bank conflicts (verified R2).
// EPI 0: qkvg epilogue (softplus x2 / gelu x2 by col>>10), store bf16.
// EPI 1: proj epilogue (+bias), store fp32.
template<int BM, int BN, int MR, int NR, int EPI>
__global__ __launch_bounds__(256) void gemm_bt(const bf16_t* __restrict__ A,
                                               const bf16_t* __restrict__ B,
                                               const float* __restrict__ bias,
                                               void* __restrict__ Cout,
                                               int M, int N, int K) {
    constexpr int WCOLS = BN / (NR * 16);
    constexpr int WROWS = BM / (MR * 16);
    static_assert(WROWS * WCOLS == 4, "4 waves");
    constexpr int ASEG = BM / 64, BSEG = BN / 64;   // staging instrs per thread
    constexpr int LOADS = ASEG + BSEG;
    __shared__ bf16_t As[2][BM * 32];
    __shared__ bf16_t Bs[2][BN * 32];
    const int tid = threadIdx.x;
    const int lane = tid & 63;
    const int w = tid >> 6;
    const int wr = w / WCOLS, wc = w % WCOLS;
    const int NTM = M / BM;
    const int bid = blockIdx.x;                     // m-fastest: consecutive blocks share B-panel
    const int m0 = (bid % NTM) * BM, n0 = (bid / NTM) * BN;
    const int l15 = lane & 15, lg = lane >> 4;
    const int srow = lane >> 2, pos = lane & 3;

    f32x4 acc[MR][NR] = {};
    const int TNUM = K / 32;

    auto stage = [&](int buf, int k0) {
#pragma unroll
        for (int t = 0; t < ASEG; ++t) {
            int s = w + t * 4;
            int row = s * 16 + srow;
            int ch = pos ^ ((row >> 1) & 3);
            gload_lds16(&A[(size_t)(m0 + row) * K + k0 + ch * 8], &As[buf][s * 512]);
        }
#pragma unroll
        for (int t = 0; t < BSEG; ++t) {
            int s = w + t * 4;
            int row = s * 16 + srow;
            int ch = pos ^ ((row >> 1) & 3);
            gload_lds16(&B[(size_t)(n0 + row) * K + k0 + ch * 8], &Bs[buf][s * 512]);
        }
    };

    stage(0, 0);
    int cur = 0;
    for (int t = 0; t < TNUM; ++t) {
        if (t + 1 < TNUM) {
            stage(cur ^ 1, (t + 1) * 32);   // issue next tile; stays in flight
            wait_vmcnt<LOADS>();            // wait only for current tile's loads
        } else {
            wait_vmcnt<0>();
        }
        __builtin_amdgcn_s_barrier();       // raw barrier: no vmcnt(0) drain
        __builtin_amdgcn_sched_barrier(0);

        const bf16_t* Ac = As[cur];
        const bf16_t* Bc = Bs[cur];
        bf16x8 af[MR], bfr[NR];
#pragma unroll
        for (int i = 0; i < MR; ++i) {
            int ar = wr * MR * 16 + i * 16 + l15;
            af[i] = *(const bf16x8*)(&Ac[ar * 32 + (lg ^ ((ar >> 1) & 3)) * 8]);
        }
#pragma unroll
        for (int j = 0; j < NR; ++j) {
            int br = wc * NR * 16 + j * 16 + l15;
            bfr[j] = *(const bf16x8*)(&Bc[br * 32 + (lg ^ ((br >> 1) & 3)) * 8]);
        }
#pragma unroll
        for (int i = 0; i < MR; ++i)
#pragma unroll
            for (int j = 0; j < NR; ++j)
                acc[i][j] = __builtin_amdgcn_mfma_f32_16x16x32_bf16(af[i], bfr[j], acc[i][j], 0, 0, 0);
        __builtin_amdgcn_sched_barrier(0);
        __builtin_amdgcn_s_barrier();       // all reads of cur done before overwrite
        cur ^= 1;
    }

    // epilogue: C/D layout col = lane&15, row = (lane>>4)*4 + reg
#pragma unroll
    for (int i = 0; i < MR; ++i) {
        int gm_base = m0 + wr * MR * 16 + i * 16 + lg * 4;
#pragma unroll
        for (int j = 0; j < NR; ++j) {
            int gn = n0 + wc * NR * 16 + j * 16 + l15;
            float bv = bias[gn];
#pragma unroll
            for (int r = 0; r < 4; ++r) {
                int gm = gm_base + r;
                float v = acc[i][j][r] + bv;
                if (EPI == 0) {
                    float a;
                    if ((gn >> 10) < 2) {
                        a = fmaxf(v, 0.f) + log1pf(expf(-fabsf(v)));          // softplus
                    } else {
                        a = 0.5f * v * (1.f + erff(v * 0.70710678118654752f)); // exact gelu
                    }
                    ((bf16_t*)Cout)[(size_t)gm * N + gn] = (bf16_t)a;
                } else {
                    ((float*)Cout)[(size_t)gm * N + gn] = v;
                }
            }
        }
    }
}

// ---------------- A = K^T Q partials per (b,h), 8 token chunks ----------------
// qkvg layout: [(b*1024+n)*4096 + s*1024 + h*64 + e], s in {q,k,v,g}
__global__ __launch_bounds__(256) void attn_A(const bf16_t* __restrict__ qkvg,
                                              float* __restrict__ Apart) {
    const int bh = blockIdx.x;           // 0..31
    const int p = blockIdx.y;            // 0..7
    const int b = bh >> 4, h = bh & 15;
    const int tid = threadIdx.x;
    __shared__ float ks[32][64];
    __shared__ float qs[32][64];
    float acc[4][4] = {};
    const int dg = tid >> 4, eg = tid & 15;
    const int stok = tid >> 3, se0 = (tid & 7) * 8;
    const size_t base = ((size_t)b * 1024) * 4096 + (size_t)h * 64;

    for (int t0 = p * 128; t0 < p * 128 + 128; t0 += 32) {
        __syncthreads();
        size_t rowb = base + (size_t)(t0 + stok) * 4096;
        bf16x8 qv8 = *(const bf16x8*)(&qkvg[rowb + se0]);
        bf16x8 kv8 = *(const bf16x8*)(&qkvg[rowb + 1024 + se0]);
#pragma unroll
        for (int jj = 0; jj < 8; ++jj) {
            qs[stok][se0 + jj] = (float)qv8[jj];
            ks[stok][se0 + jj] = (float)kv8[jj];
        }
        __syncthreads();
#pragma unroll 8
        for (int tt = 0; tt < 32; ++tt) {
            f32x4 kv = *(const f32x4*)(&ks[tt][dg * 4]);
            f32x4 qv = *(const f32x4*)(&qs[tt][eg * 4]);
#pragma unroll
            for (int i = 0; i < 4; ++i)
#pragma unroll
                for (int j = 0; j < 4; ++j) acc[i][j] += kv[i] * qv[j];
        }
    }
    float* dst = Apart + ((size_t)p * 32 + bh) * 4096;
#pragma unroll
    for (int i = 0; i < 4; ++i)
#pragma unroll
        for (int j = 0; j < 4; ++j)
            dst[(dg * 4 + i) * 64 + eg * 4 + j] = acc[i][j];
}

// ---------------- reduce partials -> A, compute z ----------------
__global__ __launch_bounds__(256) void reduce_A_z(const float* __restrict__ Apart,
                                                  float* __restrict__ A,
                                                  float* __restrict__ z) {
    const int bh = blockIdx.x;
    const int tid = threadIdx.x;
    __shared__ float As[4096];
    for (int i0 = tid * 4; i0 < 4096; i0 += 1024) {
        f32x4 s = {};
#pragma unroll
        for (int p = 0; p < 8; ++p) {
            f32x4 v = *(const f32x4*)(&Apart[((size_t)p * 32 + bh) * 4096 + i0]);
            s += v;
        }
        *(f32x4*)(&As[i0]) = s;
        *(f32x4*)(&A[(size_t)bh * 4096 + i0]) = s;
    }
    __syncthreads();
    if (tid < 64) {
        float s = 0.f;
#pragma unroll 8
        for (int d = 0; d < 64; ++d) s += As[d * 64 + tid];
        z[bh * 64 + tid] = 1.0f / (s * 0.125f + 1024.0f);
    }
}

// ---------------- Y = ((SCALE*V@A + V) * z * g), scrambled-reshaped, bf16 ----------------
__global__ __launch_bounds__(256) void out_Y(const bf16_t* __restrict__ qkvg,
                                             const float* __restrict__ A,
                                             const float* __restrict__ z,
                                             bf16_t* __restrict__ Y) {
    const int bh = blockIdx.x;
    const int b = bh >> 4, h = bh & 15;
    const int chunk = blockIdx.y;        // 0..15 -> 64 tokens
    const int tid = threadIdx.x;
    __shared__ float As[64][64];         // A[d][e]
    __shared__ float vs[32][64];
    __shared__ float zs[64];
    for (int i = tid; i < 4096; i += 256) As[i >> 6][i & 63] = A[(size_t)bh * 4096 + i];
    if (tid < 64) zs[tid] = z[bh * 64 + tid];
    const size_t base = ((size_t)b * 1024) * 4096 + (size_t)h * 64;
    const int e = tid & 63, trow = tid >> 6;
    const int stok = tid >> 3, se0 = (tid & 7) * 8;

    for (int t0 = chunk * 64; t0 < chunk * 64 + 64; t0 += 32) {
        __syncthreads();
        bf16x8 vv8 = *(const bf16x8*)(&qkvg[base + (size_t)(t0 + stok) * 4096 + 2048 + se0]);
#pragma unroll
        for (int jj = 0; jj < 8; ++jj) vs[stok][se0 + jj] = (float)vv8[jj];
        __syncthreads();
#pragma unroll
        for (int kk = 0; kk < 8; ++kk) {
            int ml = trow * 8 + kk;
            int m = t0 + ml;
            float s = 0.f;
#pragma unroll 8
            for (int d = 0; d < 64; ++d) s += vs[ml][d] * As[d][e];
            float g = (float)qkvg[base + (size_t)m * 4096 + 3072 + e];
            float o = (s * 0.125f + vs[ml][e]) * zs[e] * g;
            Y[((size_t)b * 1024 + h * 64 + (m >> 4)) * 1024 + ((m & 15) << 6) + e] = (bf16_t)o;
        }
    }
}

extern "C" void kernel_launch(void* const* d_in, const int* in_sizes, int n_in,
                              void* d_out, int out_size, void* d_ws, size_t ws_size,
                              hipStream_t stream) {
    const float* x      = (const float*)d_in[0];
    const float* w_qkvg = (const float*)d_in[1];
    const float* b_qkvg = (const float*)d_in[2];
    const float* w_proj = (const float*)d_in[3];
    const float* b_proj = (const float*)d_in[4];

    char* p = (char*)d_ws;
    bf16_t* xb    = (bf16_t*)p; p += (size_t)2048 * 1024 * 2;
    bf16_t* w1b   = (bf16_t*)p; p += (size_t)4096 * 1024 * 2;
    bf16_t* w2b   = (bf16_t*)p; p += (size_t)1024 * 1024 * 2;
    bf16_t* qkvg  = (bf16_t*)p; p += (size_t)2048 * 4096 * 2;
    float*  Apart = (float*)p;  p += (size_t)8 * 32 * 4096 * 4;
    float*  Afull = (float*)p;  p += (size_t)32 * 4096 * 4;
    float*  zbuf  = (float*)p;  p += (size_t)32 * 64 * 4;
    bf16_t* Ybuf  = (bf16_t*)p; p += (size_t)2048 * 1024 * 2;

    // quad counts: x 524288, w_qkvg 1048576, w_proj 262144 -> 7168 blocks
    cvt3<<<7168, 256, 0, stream>>>(x, xb, 524288, w_qkvg, w1b, 1048576, w_proj, w2b, 262144);

    // GEMM1: 2048x4096x1024, 128x64 tiles -> 1024 blocks (4/CU)
    gemm_bt<128, 64, 4, 2, 0><<<16 * 64, 256, 0, stream>>>(xb, w1b, b_qkvg, (void*)qkvg, 2048, 4096, 1024);
    attn_A<<<dim3(32, 8), 256, 0, stream>>>(qkvg, Apart);
    reduce_A_z<<<32, 256, 0, stream>>>(Apart, Afull, zbuf);
    out_Y<<<dim3(32, 16), 256, 0, stream>>>(qkvg, Afull, zbuf, Ybuf);
    // GEMM2: 2048x1024x1024, 64x64 tiles -> 512 blocks (2/CU)
    gemm_bt<64, 64, 2, 2, 1><<<32 * 16, 256, 0, stream>>>(Ybuf, w2b, b_proj, d_out, 2048, 1024, 1024);
}